// Round 3
// baseline (634.750 us; speedup 1.0000x reference)
//
#include <hip/hip_runtime.h>
#include <cstdint>

#define AS1 __attribute__((address_space(1)))
#define AS3 __attribute__((address_space(3)))

// Problem constants (fixed by setup_inputs)
constexpr int B  = 4;
constexpr int C  = 32;
constexpr int H  = 512;
constexpr int Wd = 960;
constexpr int Ht = H / 4;    // 128
constexpr int Wt = Wd / 4;   // 240
constexpr int HW = H * Wd;

constexpr int BLKX  = 256;        // x-pixels per block
constexpr int XMARG = 56;         // left margin: disp <= 48+1+slant(~1.4) -> taps >= x-52
constexpr int SELEM = BLKX + 64;  // 320 staged floats per channel (covers [x0-56, x0+263])
constexpr int NCHUNK = (SELEM * C) / (BLKX * 4);   // 10 DMA chunks (whole 32 channels)

// out[b, k*16 + i*4 + j, ht, wt] = sum_c |fea_l[b,c,y,x] - warp(fea_r, disp_k)[b,c,y,x]|
//
// Structure (r3): ONE barrier per block. All fea_r staging (40 KB) and the
// first fea_l octet are issued before __syncthreads(); its compiler-emitted
// vmcnt(0) drain amortizes every outstanding load in a single ~HBM-latency
// wait. The 3 disparities are exactly disp_c + {-1,0,+1}, so one floor/w and
// a shared 4-tap window t[0..3] serve all three (static tap selection) ->
// 4 LDS dwords/channel instead of 6, mergeable into ds_read2_b32 pairs.
// fea_l is register-double-buffered 8 deep so the consume loop never stalls
// on a fresh HBM miss.
//
// Register regime: launch_bounds(256,4) (cap 128) is the proven allocation.
// Do NOT tighten min-waves: (256,7) forced a spill-everything allocation
// (1.19 GB scratch writes, 3x regression in r1).
__global__ __launch_bounds__(256, 4) void tile_warping_kernel(
    const float* __restrict__ tp,   // [B,3,Ht,Wt]
    const float* __restrict__ fl,   // [B,C,H,W]
    const float* __restrict__ fr,   // [B,C,H,W]
    float* __restrict__ out)        // [B,48,Ht,Wt]
{
    __shared__ float sm[SELEM * C];   // 40960 B -> 4 blocks/CU (r2 proved >4 doesn't help)

    const int lane = threadIdx.x;
    const int x0 = blockIdx.x * BLKX;
    const int y  = blockIdx.y;
    const int b  = blockIdx.z;
    const int xstart = x0 - XMARG;

    // ---- stage fea_r row segment, all 32 channels, issued back-to-back ----
    // Linear LDS fill: dest = wave-uniform base + lane*16 B (required by
    // global_load_lds); clamped slots are never read.
    const float* frrow = fr + ((size_t)b * C * H + y) * Wd;
    #pragma unroll
    for (int chunk = 0; chunk < NCHUNK; ++chunk) {
        int e   = chunk * (BLKX * 4) + lane * 4;   // element index in sm
        int ch  = e / SELEM;
        int off = e - ch * SELEM;
        int gx  = min(max(xstart + off, 0), Wd - 4);
        const float* gp = frrow + (size_t)ch * HW + gx;
        __builtin_amdgcn_global_load_lds((const AS1 float*)gp,
                                         (AS3 float*)(&sm[e]), 16, 0, 0);
    }

    // ---- per-thread setup (overlaps stage flight) ----
    const int x   = x0 + lane;
    const bool act = (x < Wd);          // only the x0=768 block has tail lanes
    const int xc  = act ? x : (Wd - 1); // clamped coord for all loads

    const int ht = y >> 2, ii = y & 3;
    const int wt = xc >> 2, jj = xc & 3;

    const int tbase = ((b * 3) * Ht + ht) * Wt + wt;
    const float dv  = tp[tbase];
    const float dxv = tp[tbase + Ht * Wt];
    const float dyv = tp[tbase + 2 * Ht * Wt];

    const float oi = (float)ii - 1.5f;
    const float oj = (float)jj - 1.5f;

    // Center disparity (disp_d = 0), same expression/rounding as reference:
    const float disp_c = ((dv + 0.0f) + oi * dyv) + oj * dxv;
    const float xs_c = (float)xc - disp_c;
    // xs for the +-1 disparities is an EXACT fp32 shift of xs_c:
    const float xs0 = xs_c + 1.0f;   // disp_d = -1
    const float xs2 = xs_c - 1.0f;   // disp_d = +1

    const float ff = floorf(xs_c);
    const float w  = xs_c - ff;      // shared fractional weight (exact shift)
    const float w1 = 1.0f - w;

    const bool val0 = (xs0  >= 0.0f) && (xs0  <= (float)(Wd - 1));
    const bool val1 = (xs_c >= 0.0f) && (xs_c <= (float)(Wd - 1));
    const bool val2 = (xs2  >= 0.0f) && (xs2  <= (float)(Wd - 1));

    // 4-tap window base: taps at positions i_c-1 .. i_c+2.
    // Margins guarantee in-range for every case that can contribute
    // (same disp-bound argument as the staging margins); clamp is
    // belt-and-braces for pathological tails (already-invalid lanes).
    const int iw = (int)ff - 1;
    const int ow = min(max(iw - xstart, 0), SELEM - 4);

    const float* flp = fl + ((size_t)b * C * H + y) * Wd + xc;

    // First fea_l octet issued before the barrier: drained for free.
    float la[8], lb[8];
    #pragma unroll
    for (int j = 0; j < 8; ++j)
        la[j] = flp[(size_t)j * HW];

    __syncthreads();   // single vmcnt(0) drain: stages + la land together

    float s0 = 0.f, s1 = 0.f, s2 = 0.f;

    #pragma unroll
    for (int oct = 0; oct < 4; ++oct) {
        float* cur = (oct & 1) ? lb : la;   // static after full unroll
        float* nxt = (oct & 1) ? la : lb;
        if (oct < 3) {
            #pragma unroll
            for (int j = 0; j < 8; ++j)
                nxt[j] = flp[(size_t)((oct + 1) * 8 + j) * HW];
        }
        #pragma unroll
        for (int j = 0; j < 8; ++j) {
            const int c = oct * 8 + j;
            const float* bp = sm + c * SELEM + ow;
            // 4 consecutive dwords -> compiler merges to ds_read2_b32 x2
            float t0 = bp[0], t1 = bp[1], t2 = bp[2], t3 = bp[3];
            // k=0 (disp-1): taps i_c+1, i_c+2 ; k=1: i_c, i_c+1 ; k=2: i_c-1, i_c
            float wv0 = val0 ? (t2 * w1 + t3 * w) : 0.f;
            float wv1 = val1 ? (t1 * w1 + t2 * w) : 0.f;
            float wv2 = val2 ? (t0 * w1 + t1 * w) : 0.f;
            float l = cur[j];
            s0 += fabsf(l - wv0);
            s1 += fabsf(l - wv1);
            s2 += fabsf(l - wv2);
        }
    }

    if (act) {
        const int obase = ((b * 48) * Ht + ht) * Wt + wt;
        out[obase + (0 * 16 + ii * 4 + jj) * (Ht * Wt)] = s0;
        out[obase + (1 * 16 + ii * 4 + jj) * (Ht * Wt)] = s1;
        out[obase + (2 * 16 + ii * 4 + jj) * (Ht * Wt)] = s2;
    }
}

extern "C" void kernel_launch(void* const* d_in, const int* in_sizes, int n_in,
                              void* d_out, int out_size, void* d_ws, size_t ws_size,
                              hipStream_t stream) {
    const float* tp = (const float*)d_in[0];
    const float* fl = (const float*)d_in[1];
    const float* fr = (const float*)d_in[2];
    float* out = (float*)d_out;

    dim3 grid((Wd + BLKX - 1) / BLKX, H, B);   // (4, 512, 4)
    tile_warping_kernel<<<grid, 256, 0, stream>>>(tp, fl, fr, out);
}